// Round 8
// baseline (316.588 us; speedup 1.0000x reference)
//
#include <hip/hip_runtime.h>

typedef __attribute__((ext_vector_type(8))) __bf16 bf16x8;
typedef __attribute__((ext_vector_type(4))) float f32x4;
typedef __attribute__((ext_vector_type(4))) short short4v;

#define MFMA16(a,b,c)  __builtin_amdgcn_mfma_f32_16x16x32_bf16((a),(b),(c),0,0,0)
#define MFMA16K(a,b,c) __builtin_amdgcn_mfma_f32_16x16x16bf16_1k((a),(b),(c),0,0,0)

__device__ __forceinline__ short f2bf(float f){
  union { float f; unsigned u; } x; x.f = f;
  return (short)((x.u + 0x7fffu + ((x.u >> 16) & 1u)) >> 16);
}
__device__ __forceinline__ unsigned bits(float f){
  union { float f; unsigned u; } x; x.f = f; return x.u;
}

__device__ __forceinline__ void gld16(void* lds, const void* g){
  __builtin_amdgcn_global_load_lds(
      (const __attribute__((address_space(1))) unsigned*)g,
      (__attribute__((address_space(3))) unsigned*)lds, 16, 0, 0);
}

template<int N>
__device__ __forceinline__ void s_wait_vmcnt(){
  if constexpr (N==8)      asm volatile("s_waitcnt vmcnt(8)" ::: "memory");
  else if constexpr (N==6) asm volatile("s_waitcnt vmcnt(6)" ::: "memory");
  else if constexpr (N==4) asm volatile("s_waitcnt vmcnt(4)" ::: "memory");
  else if constexpr (N==2) asm volatile("s_waitcnt vmcnt(2)" ::: "memory");
  else                     asm volatile("s_waitcnt vmcnt(0)" ::: "memory");
}

// ---------------- elementwise converts / transposes ----------------

__global__ __launch_bounds__(256) void k_cvt8(const float* __restrict__ x,
                                              short* __restrict__ xb){
  long i = (long)blockIdx.x * 256 + threadIdx.x;       // groups of 8
  const float4* xv = (const float4*)x;
  float4 a = xv[2*i], c = xv[2*i+1];
  short s[8] = {f2bf(a.x),f2bf(a.y),f2bf(a.z),f2bf(a.w),
                f2bf(c.x),f2bf(c.y),f2bf(c.z),f2bf(c.w)};
  *(uint4*)&xb[8*i] = *(uint4*)s;
}

// W fp32 [2048][N] row-major -> Wt bf16 [N][2048]
__global__ void k_wt(const float* __restrict__ W, short* __restrict__ Wt, int N){
  __shared__ float tile[32][33];
  int tx = threadIdx.x, ty = threadIdx.y;
  int k0 = blockIdx.y*32, n0 = blockIdx.x*32;
  for (int j=0;j<32;j+=8)
    tile[ty+j][tx] = W[(size_t)(k0+ty+j)*N + n0 + tx];
  __syncthreads();
  for (int j=0;j<32;j+=8)
    Wt[(size_t)(n0+ty+j)*2048 + k0 + tx] = f2bf(tile[tx][ty+j]);
}

__global__ void k_bias(const float* __restrict__ bq, const float* __restrict__ bk,
                       const float* __restrict__ bv, float* __restrict__ outb){
  int i = blockIdx.x*256 + threadIdx.x;   // 0..3071
  float v = (i < 2048) ? bq[i] : (i < 2560 ? bk[i-2048] : bv[i-2560]);
  outb[i] = v;
}

// v-part of qkv (bf16, rows 4096, cols 2560..3071 of ld 3072) -> Vt[b][kvh][d][t]
__global__ void k_vt(const short* __restrict__ qkv, short* __restrict__ Vt){
  __shared__ short tile[32][33];
  int tx = threadIdx.x, ty = threadIdx.y;
  int t0 = blockIdx.x*32, c0 = blockIdx.y*32;
  for (int j=0;j<32;j+=8)
    tile[ty+j][tx] = qkv[(size_t)(t0+ty+j)*3072 + 2560 + c0 + tx];
  __syncthreads();
  int b = t0 >> 11, t_in_b = t0 & 2047;
  for (int j=0;j<32;j+=8){
    int col = c0 + ty + j;               // 0..511
    int kvh = col >> 7, d = col & 127;
    Vt[((size_t)((b*4 + kvh)*128 + d))*2048 + t_in_b + tx] = tile[tx][ty+j];
  }
}

// -------- 128 x (BCH*128) / BK=64 phase-split GEMM: C = A * Bt^T + bias ----
// (byte-identical to round 7.)
template<int BCH, int OUT_BF16>
__global__ __launch_bounds__(512, 2) void gemmR(const short* __restrict__ A,
    const short* __restrict__ Bt, const float* __restrict__ bias,
    void* __restrict__ Cv, int N, int K){
  constexpr int ASZ  = 8192;                 // shorts in one 128x64 chunk
  constexpr int BUFS = ASZ*(1+BCH);
  __shared__ short SM[2*BUFS];
  const int tid = threadIdx.x;
  const int w = tid >> 6, lane = tid & 63, l15 = lane & 15, quad = lane >> 4;
  const int wr = w >> 2, wc = w & 3;
  const int m0 = blockIdx.y * 128, n0 = blockIdx.x * (BCH*128);
  const int ln8 = lane >> 3;
  const int g8 = (((lane & 7) ^ ln8) << 3);            // pre-swizzled src granule
  const short* aB = A  + (size_t)(m0 + w*16 + ln8) * K + g8;
  const short* bB = Bt + (size_t)(n0 + w*16 + ln8) * K + g8;
  const int aRB = (wr*64 + l15)*64;
  const int bRB = (wc*32 + l15)*64;
  const int phys0 = ((quad     ^ (l15 & 7)) << 3);     // kk=0..31 granule
  const int phys1 = (((quad+4) ^ (l15 & 7)) << 3);     // kk=32..63 granule
  f32x4 acc[BCH][4][2] = {};
  bf16x8 aF[4][2], bF[2][2];
  const int nt = K >> 6;

#define STG_A(bufi, T) do{ \
    short* d_ = &SM[(bufi)*BUFS + w*1024]; \
    const short* s_ = aB + (size_t)(T)*64; \
    gld16(d_, s_); gld16(d_+512, s_ + (size_t)8*K); }while(0)
#define STG_B(bufi, ch, T) do{ \
    short* d_ = &SM[(bufi)*BUFS + ASZ + (ch)*ASZ + w*1024]; \
    const short* s_ = bB + (size_t)((ch)*128)*K + (size_t)(T)*64; \
    gld16(d_, s_); gld16(d_+512, s_ + (size_t)8*K); }while(0)
#define RD_A(bufi) do{ const short* p_ = &SM[(bufi)*BUFS + aRB]; \
    _Pragma("unroll") for(int m_=0;m_<4;m_++){ \
      aF[m_][0] = *(const bf16x8*)&p_[m_*1024 + phys0]; \
      aF[m_][1] = *(const bf16x8*)&p_[m_*1024 + phys1]; } }while(0)
#define RD_B(bufi, ch) do{ const short* p_ = &SM[(bufi)*BUFS + ASZ + (ch)*ASZ + bRB]; \
    _Pragma("unroll") for(int n_=0;n_<2;n_++){ \
      bF[n_][0] = *(const bf16x8*)&p_[n_*1024 + phys0]; \
      bF[n_][1] = *(const bf16x8*)&p_[n_*1024 + phys1]; } }while(0)
#define MM(ch) do{ __builtin_amdgcn_s_setprio(1); \
    _Pragma("unroll") for(int m_=0;m_<4;m_++) \
    _Pragma("unroll") for(int n_=0;n_<2;n_++){ \
      acc[ch][m_][n_] = MFMA16(aF[m_][0], bF[n_][0], acc[ch][m_][n_]); \
      acc[ch][m_][n_] = MFMA16(aF[m_][1], bF[n_][1], acc[ch][m_][n_]); } \
    __builtin_amdgcn_s_setprio(0); }while(0)
#define PH(W) do{ s_wait_vmcnt<W>(); \
    __builtin_amdgcn_s_barrier(); \
    __builtin_amdgcn_sched_barrier(0); }while(0)
#define GROUP3(T, ST1, ST2, W0, W1, W2) do{ \
    const int c_=(T)&1, n_c=c_^1; \
    PH(W0); if (ST1) STG_B(n_c,1,(T)+1); RD_A(c_); RD_B(c_,0); MM(0); \
    PH(W1); if (ST1) STG_B(n_c,2,(T)+1); RD_B(c_,1); MM(1); \
    PH(W2); if (ST2){ STG_A(c_,(T)+2); STG_B(c_,0,(T)+2); } RD_B(c_,2); MM(2); \
  }while(0)
#define GROUP2(T, ST1, ST2, W0, W1) do{ \
    const int c_=(T)&1, n_c=c_^1; \
    PH(W0); if (ST1) STG_B(n_c,1,(T)+1); RD_A(c_); RD_B(c_,0); MM(0); \
    PH(W1); if (ST2){ STG_A(c_,(T)+2); STG_B(c_,0,(T)+2); } RD_B(c_,1); MM(1); \
  }while(0)

  if constexpr (BCH == 3){
    // prologue FIFO: T0.A,T0.B0,T0.B1,T0.B2,T1.A,T1.B0  (12 ops)
    STG_A(0,0); STG_B(0,0,0); STG_B(0,1,0); STG_B(0,2,0);
    STG_A(1,1); STG_B(1,0,1);
    for (int T = 0; T < nt-2; ++T) GROUP3(T, true, true, 8,8,8);
    GROUP3(nt-2, true,  false, 8,8,8);
    GROUP3(nt-1, false, false, 4,2,0);
  } else {
    // prologue FIFO: T0.A,T0.B0,T0.B1,T1.A,T1.B0  (10 ops)
    STG_A(0,0); STG_B(0,0,0); STG_B(0,1,0);
    STG_A(1,1); STG_B(1,0,1);
    for (int T = 0; T < nt-2; ++T) GROUP2(T, true, true, 6,6);
    GROUP2(nt-2, true,  false, 6,6);
    GROUP2(nt-1, false, false, 2,0);
  }

#undef GROUP2
#undef GROUP3
#undef PH
#undef MM
#undef RD_B
#undef RD_A
#undef STG_B
#undef STG_A

  // epilogue (same arithmetic as before: acc + bias, then f2bf/float)
  float bv[BCH][2];
#pragma unroll
  for (int ch=0; ch<BCH; ch++)
#pragma unroll
    for (int n=0; n<2; n++)
      bv[ch][n] = bias[n0 + ch*128 + wc*32 + n*16 + l15];
#pragma unroll
  for (int ch=0; ch<BCH; ch++)
#pragma unroll
  for (int m=0; m<4; m++){
    int row = m0 + wr*64 + m*16 + quad*4;
#pragma unroll
    for (int n=0; n<2; n++){
      int col = n0 + ch*128 + wc*32 + n*16 + l15;
#pragma unroll
      for (int r=0; r<4; r++){
        float v = acc[ch][m][n][r] + bv[ch][n];
        if (OUT_BF16) ((short*)Cv)[(size_t)(row+r)*N + col] = f2bf(v);
        else          ((float*)Cv)[(size_t)(row+r)*N + col] = v;
      }
    }
  }
}

// ---------------- causal GQA attention, UN-PAIRED strips ------------------
// Single-variable experiment vs the round-7 passing kernel: the sp-loop
// (strip pairing) is removed; grid.x 16 -> 32; qi = (h>=8)? p : 31-p so each
// CU's round-robin block set sums to uniform 132 iters. 1024 blocks x 4
// waves -> 4 blocks/CU (128KB LDS, VGPR 96 <= 128) -> 4 waves/SIMD.
// EVERYTHING inside the per-strip body (mask, staging pointers, ds slots,
// setprio, epilogue) is verbatim from the passing kernel.
__global__ __launch_bounds__(256) void k_attn(const short* __restrict__ qkv,
                                              const short* __restrict__ Vt,
                                              short* __restrict__ attn){
  constexpr float COEF = 0.12752365f;     // (1/sqrt(128)) * log2(e)
  __shared__ short SM[16384];             // 2 buffers x (K 4096 + V 4096 shorts)
  const int tid = threadIdx.x, w = tid >> 6, lane = tid & 63;
  const int l15 = lane & 15, quad = lane >> 4;
  const int p = blockIdx.x, h = blockIdx.y, b = blockIdx.z, kvh = h >> 2;
  const int qi = ((h >> 3) & 1) ? p : 31 - p;

  // staging source pointers (per-lane); each wave stages 1/4 of each tile
  const short* kb[2];
  const short* vb[2];
#pragma unroll
  for (int j=0;j<2;j++){
    int rK = w*8 + j*4 + (lane >> 4);            // s-row 0..31
    int cK = (lane & 15) ^ (rK & 15);            // 8-short chunk of d
    kb[j] = qkv + (size_t)(b*2048 + rK)*3072 + 2048 + kvh*128 + cK*8;
    int dV = w*32 + j*16 + (lane >> 2);          // d-row 0..127
    int cV = (lane & 3) ^ (dV & 3) ^ ((dV >> 2) & 3);  // 8-short chunk of s
    vb[j] = Vt + ((size_t)((b*4 + kvh)*128 + dV))*2048 + cV*8;
  }
  short* K0 = &SM[w*1024];                // wave's slot base, buf 0
  short* V0 = &SM[4096 + w*1024];

  int buf = 0;
  // prologue: stage tile 0 into buf 0
#pragma unroll
  for (int j=0;j<2;j++){
    gld16(K0 + j*512, kb[j]);
    gld16(V0 + j*512, vb[j]);
  }

  const int qw = qi*64 + w*16;          // this wave's 16 q rows
  // Q fragments from global (B-operand layout: lane q=l15, k contiguous)
  bf16x8 qf[4];
  {
    const short* qbase = qkv + ((size_t)(b*2048 + qw + l15))*3072 + h*128 + quad*8;
#pragma unroll
    for (int d4=0;d4<4;d4++)
      qf[d4] = *(const bf16x8*)(qbase + d4*32);
  }
  f32x4 accO[8] = {};
  float lsum = 0.f;
  const int nst = 2*qi + 2;

  for (int st = 0; st < nst; st++){
    __syncthreads();                       // tile(st) in LDS[buf] complete
    const int cur = buf;
    const int nb = buf ^ 1;
    // async-stage next tile into other buffer
    if (st + 1 < nst){
      int nxt = (st + 1) * 32;
      short* Kd = &SM[nb*8192 + w*1024];
      short* Vd = &SM[nb*8192 + 4096 + w*1024];
      const size_t ko = (size_t)nxt * 3072;
#pragma unroll
      for (int j=0;j<2;j++){
        gld16(Kd + j*512, kb[j] + ko);
        gld16(Vd + j*512, vb[j] + nxt);
      }
    }
    const int s0 = st * 32;
    if (s0 <= qw + 15){                    // wave-uniform skip
      const short* Kb = &SM[cur*8192];
      const short* Vb = &SM[cur*8192 + 4096];
      bf16x8 kf[2][4];
#pragma unroll
      for (int ss=0;ss<2;ss++)
#pragma unroll
        for (int d4=0;d4<4;d4++){
          int slot = (ss*16 + l15)*16 + ((d4*4 + quad) ^ l15);
          kf[ss][d4] = *(const bf16x8*)&Kb[slot*8];
        }
      f32x4 sa[2] = {};
      __builtin_amdgcn_s_setprio(1);
#pragma unroll
      for (int d4=0;d4<4;d4++){
        sa[0] = MFMA16(kf[0][d4], qf[d4], sa[0]);
        sa[1] = MFMA16(kf[1][d4], qf[d4], sa[1]);
      }
      __builtin_amdgcn_s_setprio(0);
      short4v pf[2];
      const bool mneed = (s0 + 31 > qw);
      const int qgl = qw + l15;
#pragma unroll
      for (int sub=0;sub<2;sub++){
        float pr[4];
#pragma unroll
        for (int r=0;r<4;r++){
          float e = __builtin_amdgcn_exp2f(sa[sub][r] * COEF);
          int sg = s0 + sub*16 + quad*4 + r;
          if (mneed && (sg > qgl)) e = 0.f;
          pr[r] = e;
        }
        lsum += (pr[0]+pr[1]) + (pr[2]+pr[3]);
        union { unsigned u[2]; short4v s; } pk;
        pk.u[0] = __builtin_amdgcn_perm(bits(pr[1]), bits(pr[0]), 0x07060302u);
        pk.u[1] = __builtin_amdgcn_perm(bits(pr[3]), bits(pr[2]), 0x07060302u);
        pf[sub] = pk.s;
      }
      // O^T += V^T * P^T
      __builtin_amdgcn_s_setprio(1);
#pragma unroll
      for (int sub=0;sub<2;sub++)
#pragma unroll
        for (int dt=0;dt<8;dt++){
          int slot = (dt*16 + l15)*4 +
                     ((sub*2 + (quad>>1)) ^ (l15 & 3) ^ ((l15 >> 2) & 3));
          short4v vf = *(const short4v*)&Vb[slot*8 + (quad&1)*4];
          accO[dt] = MFMA16K(vf, pf[sub], accO[dt]);
        }
      __builtin_amdgcn_s_setprio(0);
    }
    buf = nb;
  }
  // normalize + store
  {
    float s = lsum;
    s += __shfl_xor(s, 16);
    s += __shfl_xor(s, 32);
    float inv = 1.0f / s;
    short* obase = attn + ((size_t)(b*2048 + qw + l15))*2048 + h*128 + quad*4;
#pragma unroll
    for (int dt=0;dt<8;dt++){
      float o0 = accO[dt][0]*inv, o1 = accO[dt][1]*inv;
      float o2 = accO[dt][2]*inv, o3 = accO[dt][3]*inv;
      union { unsigned u[2]; short4v s; } ok;
      ok.u[0] = __builtin_amdgcn_perm(bits(o1), bits(o0), 0x07060302u);
      ok.u[1] = __builtin_amdgcn_perm(bits(o3), bits(o2), 0x07060302u);
      *(short4v*)(obase + dt*16) = ok.s;
    }
  }
}

// ---------------- launcher ----------------
extern "C" void kernel_launch(void* const* d_in, const int* in_sizes, int n_in,
                              void* d_out, int out_size, void* d_ws, size_t ws_size,
                              hipStream_t stream){
  const float* x  = (const float*)d_in[0];
  const float* Wq = (const float*)d_in[1];
  const float* bq = (const float*)d_in[2];
  const float* Wk = (const float*)d_in[3];
  const float* bk = (const float*)d_in[4];
  const float* Wv = (const float*)d_in[5];
  const float* bv = (const float*)d_in[6];
  const float* Wo = (const float*)d_in[7];
  const float* bo = (const float*)d_in[8];
  float* out = (float*)d_out;
  char* ws = (char*)d_ws;

  short* xb    = (short*)(ws + 0);                        // 16 MB
  short* WtQKV = (short*)(ws + (size_t)16*1024*1024);     // 12 MB [3072][2048]
  short* WoT   = (short*)(ws + (size_t)28*1024*1024);     //  8 MB [2048][2048]
  float* biasQ = (float*)(ws + (size_t)36*1024*1024);     // 12 KB
  short* qkv   = (short*)(ws + (size_t)37*1024*1024);     // 24 MB [4096][3072]
  short* Vt    = (short*)(ws + (size_t)61*1024*1024);     //  4 MB [B][KVH][128][2048]
  short* attn  = (short*)(ws + 0);                        // overlay xb (disjoint lifetime)

  k_cvt8<<<4096, 256, 0, stream>>>(x, xb);
  k_wt<<<dim3(64,64), dim3(32,8), 0, stream>>>(Wq, WtQKV, 2048);
  k_wt<<<dim3(16,64), dim3(32,8), 0, stream>>>(Wk, WtQKV + (size_t)2048*2048, 512);
  k_wt<<<dim3(16,64), dim3(32,8), 0, stream>>>(Wv, WtQKV + (size_t)2560*2048, 512);
  k_wt<<<dim3(64,64), dim3(32,8), 0, stream>>>(Wo, WoT, 2048);
  k_bias<<<12, 256, 0, stream>>>(bq, bk, bv, biasQ);
  gemmR<3,1><<<dim3(8,32), 512, 0, stream>>>(xb, WtQKV, biasQ, qkv, 3072, 2048);
  k_vt<<<dim3(128,16), dim3(32,8), 0, stream>>>(qkv, Vt);
  k_attn<<<dim3(32,16,2), 256, 0, stream>>>(qkv, Vt, attn);
  gemmR<2,0><<<dim3(8,32), 512, 0, stream>>>(attn, WoT, bo, out, 2048, 2048);
}

// Round 10
// 293.573 us; speedup vs baseline: 1.0784x; 1.0784x over previous
//
#include <hip/hip_runtime.h>

typedef __attribute__((ext_vector_type(8))) __bf16 bf16x8;
typedef __attribute__((ext_vector_type(4))) float f32x4;
typedef __attribute__((ext_vector_type(4))) short short4v;

#define MFMA16(a,b,c)  __builtin_amdgcn_mfma_f32_16x16x32_bf16((a),(b),(c),0,0,0)
#define MFMA16K(a,b,c) __builtin_amdgcn_mfma_f32_16x16x16bf16_1k((a),(b),(c),0,0,0)

__device__ __forceinline__ short f2bf(float f){
  union { float f; unsigned u; } x; x.f = f;
  return (short)((x.u + 0x7fffu + ((x.u >> 16) & 1u)) >> 16);
}
__device__ __forceinline__ unsigned bits(float f){
  union { float f; unsigned u; } x; x.f = f; return x.u;
}

__device__ __forceinline__ void gld16(void* lds, const void* g){
  __builtin_amdgcn_global_load_lds(
      (const __attribute__((address_space(1))) unsigned*)g,
      (__attribute__((address_space(3))) unsigned*)lds, 16, 0, 0);
}

template<int N>
__device__ __forceinline__ void s_wait_vmcnt(){
  if constexpr (N==8)      asm volatile("s_waitcnt vmcnt(8)" ::: "memory");
  else if constexpr (N==6) asm volatile("s_waitcnt vmcnt(6)" ::: "memory");
  else if constexpr (N==4) asm volatile("s_waitcnt vmcnt(4)" ::: "memory");
  else if constexpr (N==2) asm volatile("s_waitcnt vmcnt(2)" ::: "memory");
  else                     asm volatile("s_waitcnt vmcnt(0)" ::: "memory");
}

// ---------------- elementwise converts / transposes ----------------

__global__ __launch_bounds__(256) void k_cvt8(const float* __restrict__ x,
                                              short* __restrict__ xb){
  long i = (long)blockIdx.x * 256 + threadIdx.x;       // groups of 8
  const float4* xv = (const float4*)x;
  float4 a = xv[2*i], c = xv[2*i+1];
  short s[8] = {f2bf(a.x),f2bf(a.y),f2bf(a.z),f2bf(a.w),
                f2bf(c.x),f2bf(c.y),f2bf(c.z),f2bf(c.w)};
  *(uint4*)&xb[8*i] = *(uint4*)s;
}

// ALL weight transposes (Wq,Wk,Wv,Wo) + bias concat in ONE kernel.
// blockIdx.x ranges: [0,64) Wq | [64,80) Wk | [80,96) Wv | [96,160) Wo |
// [160,172) bias. Per-tile math verbatim from the separate kernels.
__global__ void k_wtall(const float* __restrict__ Wq, const float* __restrict__ Wk,
                        const float* __restrict__ Wv, const float* __restrict__ Wo,
                        const float* __restrict__ bq, const float* __restrict__ bk,
                        const float* __restrict__ bv,
                        short* __restrict__ WtQKV, short* __restrict__ WoT,
                        float* __restrict__ biasQ){
  __shared__ float tile[32][33];
  int tx = threadIdx.x, ty = threadIdx.y;
  int bx = blockIdx.x;
  if (bx >= 160){                          // bias part (12 blocks x 256 thr)
    int i = (bx - 160)*256 + ty*32 + tx;   // 0..3071
    float v = (i < 2048) ? bq[i] : (i < 2560 ? bk[i-2048] : bv[i-2560]);
    biasQ[i] = v;
    return;
  }
  const float* W; short* Wt; int N, nb0;
  if (bx < 64)      { W = Wq; Wt = WtQKV;                      N = 2048; nb0 = bx; }
  else if (bx < 80) { W = Wk; Wt = WtQKV + (size_t)2048*2048;  N = 512;  nb0 = bx-64; }
  else if (bx < 96) { W = Wv; Wt = WtQKV + (size_t)2560*2048;  N = 512;  nb0 = bx-80; }
  else              { W = Wo; Wt = WoT;                        N = 2048; nb0 = bx-96; }
  int k0 = blockIdx.y*32, n0 = nb0*32;
  for (int j=0;j<32;j+=8)
    tile[ty+j][tx] = W[(size_t)(k0+ty+j)*N + n0 + tx];
  __syncthreads();
  for (int j=0;j<32;j+=8)
    Wt[(size_t)(n0+ty+j)*2048 + k0 + tx] = f2bf(tile[tx][ty+j]);
}

// -------- 128 x (BCH*128) / BK=64 phase-split GEMM: C = A * Bt^T + bias ----
// (pipeline byte-identical to round 7.) WVT=1: V-columns (col>=2560 of the
// QKV output) are ALSO stored (same f2bf short -> bit-identical to the old
// k_vt copy) into Vt[b][kvh][d][t] -- fuses k_vt away.
template<int BCH, int OUT_BF16, int WVT>
__global__ __launch_bounds__(512, 2) void gemmR(const short* __restrict__ A,
    const short* __restrict__ Bt, const float* __restrict__ bias,
    void* __restrict__ Cv, short* __restrict__ Vt, int N, int K){
  constexpr int ASZ  = 8192;                 // shorts in one 128x64 chunk
  constexpr int BUFS = ASZ*(1+BCH);
  __shared__ short SM[2*BUFS];
  const int tid = threadIdx.x;
  const int w = tid >> 6, lane = tid & 63, l15 = lane & 15, quad = lane >> 4;
  const int wr = w >> 2, wc = w & 3;
  const int m0 = blockIdx.y * 128, n0 = blockIdx.x * (BCH*128);
  const int ln8 = lane >> 3;
  const int g8 = (((lane & 7) ^ ln8) << 3);            // pre-swizzled src granule
  const short* aB = A  + (size_t)(m0 + w*16 + ln8) * K + g8;
  const short* bB = Bt + (size_t)(n0 + w*16 + ln8) * K + g8;
  const int aRB = (wr*64 + l15)*64;
  const int bRB = (wc*32 + l15)*64;
  const int phys0 = ((quad     ^ (l15 & 7)) << 3);     // kk=0..31 granule
  const int phys1 = (((quad+4) ^ (l15 & 7)) << 3);     // kk=32..63 granule
  f32x4 acc[BCH][4][2] = {};
  bf16x8 aF[4][2], bF[2][2];
  const int nt = K >> 6;

#define STG_A(bufi, T) do{ \
    short* d_ = &SM[(bufi)*BUFS + w*1024]; \
    const short* s_ = aB + (size_t)(T)*64; \
    gld16(d_, s_); gld16(d_+512, s_ + (size_t)8*K); }while(0)
#define STG_B(bufi, ch, T) do{ \
    short* d_ = &SM[(bufi)*BUFS + ASZ + (ch)*ASZ + w*1024]; \
    const short* s_ = bB + (size_t)((ch)*128)*K + (size_t)(T)*64; \
    gld16(d_, s_); gld16(d_+512, s_ + (size_t)8*K); }while(0)
#define RD_A(bufi) do{ const short* p_ = &SM[(bufi)*BUFS + aRB]; \
    _Pragma("unroll") for(int m_=0;m_<4;m_++){ \
      aF[m_][0] = *(const bf16x8*)&p_[m_*1024 + phys0]; \
      aF[m_][1] = *(const bf16x8*)&p_[m_*1024 + phys1]; } }while(0)
#define RD_B(bufi, ch) do{ const short* p_ = &SM[(bufi)*BUFS + ASZ + (ch)*ASZ + bRB]; \
    _Pragma("unroll") for(int n_=0;n_<2;n_++){ \
      bF[n_][0] = *(const bf16x8*)&p_[n_*1024 + phys0]; \
      bF[n_][1] = *(const bf16x8*)&p_[n_*1024 + phys1]; } }while(0)
#define MM(ch) do{ __builtin_amdgcn_s_setprio(1); \
    _Pragma("unroll") for(int m_=0;m_<4;m_++) \
    _Pragma("unroll") for(int n_=0;n_<2;n_++){ \
      acc[ch][m_][n_] = MFMA16(aF[m_][0], bF[n_][0], acc[ch][m_][n_]); \
      acc[ch][m_][n_] = MFMA16(aF[m_][1], bF[n_][1], acc[ch][m_][n_]); } \
    __builtin_amdgcn_s_setprio(0); }while(0)
#define PH(W) do{ s_wait_vmcnt<W>(); \
    __builtin_amdgcn_s_barrier(); \
    __builtin_amdgcn_sched_barrier(0); }while(0)
#define GROUP3(T, ST1, ST2, W0, W1, W2) do{ \
    const int c_=(T)&1, n_c=c_^1; \
    PH(W0); if (ST1) STG_B(n_c,1,(T)+1); RD_A(c_); RD_B(c_,0); MM(0); \
    PH(W1); if (ST1) STG_B(n_c,2,(T)+1); RD_B(c_,1); MM(1); \
    PH(W2); if (ST2){ STG_A(c_,(T)+2); STG_B(c_,0,(T)+2); } RD_B(c_,2); MM(2); \
  }while(0)
#define GROUP2(T, ST1, ST2, W0, W1) do{ \
    const int c_=(T)&1, n_c=c_^1; \
    PH(W0); if (ST1) STG_B(n_c,1,(T)+1); RD_A(c_); RD_B(c_,0); MM(0); \
    PH(W1); if (ST2){ STG_A(c_,(T)+2); STG_B(c_,0,(T)+2); } RD_B(c_,1); MM(1); \
  }while(0)

  if constexpr (BCH == 3){
    // prologue FIFO: T0.A,T0.B0,T0.B1,T0.B2,T1.A,T1.B0  (12 ops)
    STG_A(0,0); STG_B(0,0,0); STG_B(0,1,0); STG_B(0,2,0);
    STG_A(1,1); STG_B(1,0,1);
    for (int T = 0; T < nt-2; ++T) GROUP3(T, true, true, 8,8,8);
    GROUP3(nt-2, true,  false, 8,8,8);
    GROUP3(nt-1, false, false, 4,2,0);
  } else {
    // prologue FIFO: T0.A,T0.B0,T0.B1,T1.A,T1.B0  (10 ops)
    STG_A(0,0); STG_B(0,0,0); STG_B(0,1,0);
    STG_A(1,1); STG_B(1,0,1);
    for (int T = 0; T < nt-2; ++T) GROUP2(T, true, true, 6,6);
    GROUP2(nt-2, true,  false, 6,6);
    GROUP2(nt-1, false, false, 2,0);
  }

#undef GROUP2
#undef GROUP3
#undef PH
#undef MM
#undef RD_B
#undef RD_A
#undef STG_B
#undef STG_A

  // epilogue (same arithmetic as before: acc + bias, then f2bf/float)
  float bv[BCH][2];
#pragma unroll
  for (int ch=0; ch<BCH; ch++)
#pragma unroll
    for (int n=0; n<2; n++)
      bv[ch][n] = bias[n0 + ch*128 + wc*32 + n*16 + l15];
#pragma unroll
  for (int ch=0; ch<BCH; ch++)
#pragma unroll
  for (int m=0; m<4; m++){
    int row = m0 + wr*64 + m*16 + quad*4;
#pragma unroll
    for (int n=0; n<2; n++){
      int col = n0 + ch*128 + wc*32 + n*16 + l15;
#pragma unroll
      for (int r=0; r<4; r++){
        float v = acc[ch][m][n][r] + bv[ch][n];
        if (OUT_BF16){
          short sv = f2bf(v);
          ((short*)Cv)[(size_t)(row+r)*N + col] = sv;
          if (WVT && col >= 2560){           // lane-uniform per (ch,n)
            int c2 = col - 2560;             // kvh*128 + d
            int rr = row + r;                // b*2048 + t
            Vt[((size_t)((rr>>11)*4 + (c2>>7))*128 + (c2&127))*2048 + (rr&2047)] = sv;
          }
        } else {
          ((float*)Cv)[(size_t)(row+r)*N + col] = v;
        }
      }
    }
  }
}

// ---------------- causal GQA attention, LPT-scheduled strips --------------
// Body verbatim from the round-8 PASSING kernel; ONLY the blockIdx ->
// (qi,h,b) map changed to global longest-first (LPT): lin = bx+32*by+512*bz;
// qi = 31-(lin>>5) (first 512 dispatched blocks are the longest -> they
// start first; short blocks backfill -> no straggler tail). Bijective:
// group g=lin>>5 fixes qi; idx=lin&31 spans (h,b) = (idx&15, idx>>4).
// 1024 blocks x 4 waves -> 4 blocks/CU -> 4 waves/SIMD.
__global__ __launch_bounds__(256) void k_attn(const short* __restrict__ qkv,
                                              const short* __restrict__ Vt,
                                              short* __restrict__ attn){
  constexpr float COEF = 0.12752365f;     // (1/sqrt(128)) * log2(e)
  __shared__ short SM[16384];             // 2 buffers x (K 4096 + V 4096 shorts)
  const int tid = threadIdx.x, w = tid >> 6, lane = tid & 63;
  const int l15 = lane & 15, quad = lane >> 4;
  const int lin = (int)blockIdx.x + 32*(int)blockIdx.y + 512*(int)blockIdx.z;
  const int qi  = 31 - (lin >> 5);
  const int idx = lin & 31;
  const int h = idx & 15, b = idx >> 4, kvh = h >> 2;

  // staging source pointers (per-lane); each wave stages 1/4 of each tile
  const short* kb[2];
  const short* vb[2];
#pragma unroll
  for (int j=0;j<2;j++){
    int rK = w*8 + j*4 + (lane >> 4);            // s-row 0..31
    int cK = (lane & 15) ^ (rK & 15);            // 8-short chunk of d
    kb[j] = qkv + (size_t)(b*2048 + rK)*3072 + 2048 + kvh*128 + cK*8;
    int dV = w*32 + j*16 + (lane >> 2);          // d-row 0..127
    int cV = (lane & 3) ^ (dV & 3) ^ ((dV >> 2) & 3);  // 8-short chunk of s
    vb[j] = Vt + ((size_t)((b*4 + kvh)*128 + dV))*2048 + cV*8;
  }
  short* K0 = &SM[w*1024];                // wave's slot base, buf 0
  short* V0 = &SM[4096 + w*1024];

  int buf = 0;
  // prologue: stage tile 0 into buf 0
#pragma unroll
  for (int j=0;j<2;j++){
    gld16(K0 + j*512, kb[j]);
    gld16(V0 + j*512, vb[j]);
  }

  const int qw = qi*64 + w*16;          // this wave's 16 q rows
  // Q fragments from global (B-operand layout: lane q=l15, k contiguous)
  bf16x8 qf[4];
  {
    const short* qbase = qkv + ((size_t)(b*2048 + qw + l15))*3072 + h*128 + quad*8;
#pragma unroll
    for (int d4=0;d4<4;d4++)
      qf[d4] = *(const bf16x8*)(qbase + d4*32);
  }
  f32x4 accO[8] = {};
  float lsum = 0.f;
  const int nst = 2*qi + 2;

  for (int st = 0; st < nst; st++){
    __syncthreads();                       // tile(st) in LDS[buf] complete
    const int cur = buf;
    const int nb = buf ^ 1;
    // async-stage next tile into other buffer
    if (st + 1 < nst){
      int nxt = (st + 1) * 32;
      short* Kd = &SM[nb*8192 + w*1024];
      short* Vd = &SM[nb*8192 + 4096 + w*1024];
      const size_t ko = (size_t)nxt * 3072;
#pragma unroll
      for (int j=0;j<2;j++){
        gld16(Kd + j*512, kb[j] + ko);
        gld16(Vd + j*512, vb[j] + nxt);
      }
    }
    const int s0 = st * 32;
    if (s0 <= qw + 15){                    // wave-uniform skip
      const short* Kb = &SM[cur*8192];
      const short* Vb = &SM[cur*8192 + 4096];
      bf16x8 kf[2][4];
#pragma unroll
      for (int ss=0;ss<2;ss++)
#pragma unroll
        for (int d4=0;d4<4;d4++){
          int slot = (ss*16 + l15)*16 + ((d4*4 + quad) ^ l15);
          kf[ss][d4] = *(const bf16x8*)&Kb[slot*8];
        }
      f32x4 sa[2] = {};
      __builtin_amdgcn_s_setprio(1);
#pragma unroll
      for (int d4=0;d4<4;d4++){
        sa[0] = MFMA16(kf[0][d4], qf[d4], sa[0]);
        sa[1] = MFMA16(kf[1][d4], qf[d4], sa[1]);
      }
      __builtin_amdgcn_s_setprio(0);
      short4v pf[2];
      const bool mneed = (s0 + 31 > qw);
      const int qgl = qw + l15;
#pragma unroll
      for (int sub=0;sub<2;sub++){
        float pr[4];
#pragma unroll
        for (int r=0;r<4;r++){
          float e = __builtin_amdgcn_exp2f(sa[sub][r] * COEF);
          int sg = s0 + sub*16 + quad*4 + r;
          if (mneed && (sg > qgl)) e = 0.f;
          pr[r] = e;
        }
        lsum += (pr[0]+pr[1]) + (pr[2]+pr[3]);
        union { unsigned u[2]; short4v s; } pk;
        pk.u[0] = __builtin_amdgcn_perm(bits(pr[1]), bits(pr[0]), 0x07060302u);
        pk.u[1] = __builtin_amdgcn_perm(bits(pr[3]), bits(pr[2]), 0x07060302u);
        pf[sub] = pk.s;
      }
      // O^T += V^T * P^T
      __builtin_amdgcn_s_setprio(1);
#pragma unroll
      for (int sub=0;sub<2;sub++)
#pragma unroll
        for (int dt=0;dt<8;dt++){
          int slot = (dt*16 + l15)*4 +
                     ((sub*2 + (quad>>1)) ^ (l15 & 3) ^ ((l15 >> 2) & 3));
          short4v vf = *(const short4v*)&Vb[slot*8 + (quad&1)*4];
          accO[dt] = MFMA16K(vf, pf[sub], accO[dt]);
        }
      __builtin_amdgcn_s_setprio(0);
    }
    buf = nb;
  }
  // normalize + store
  {
    float s = lsum;
    s += __shfl_xor(s, 16);
    s += __shfl_xor(s, 32);
    float inv = 1.0f / s;
    short* obase = attn + ((size_t)(b*2048 + qw + l15))*2048 + h*128 + quad*4;
#pragma unroll
    for (int dt=0;dt<8;dt++){
      float o0 = accO[dt][0]*inv, o1 = accO[dt][1]*inv;
      float o2 = accO[dt][2]*inv, o3 = accO[dt][3]*inv;
      union { unsigned u[2]; short4v s; } ok;
      ok.u[0] = __builtin_amdgcn_perm(bits(o1), bits(o0), 0x07060302u);
      ok.u[1] = __builtin_amdgcn_perm(bits(o3), bits(o2), 0x07060302u);
      *(short4v*)(obase + dt*16) = ok.s;
    }
  }
}

// ---------------- launcher ----------------
extern "C" void kernel_launch(void* const* d_in, const int* in_sizes, int n_in,
                              void* d_out, int out_size, void* d_ws, size_t ws_size,
                              hipStream_t stream){
  const float* x  = (const float*)d_in[0];
  const float* Wq = (const float*)d_in[1];
  const float* bq = (const float*)d_in[2];
  const float* Wk = (const float*)d_in[3];
  const float* bk = (const float*)d_in[4];
  const float* Wv = (const float*)d_in[5];
  const float* bv = (const float*)d_in[6];
  const float* Wo = (const float*)d_in[7];
  const float* bo = (const float*)d_in[8];
  float* out = (float*)d_out;
  char* ws = (char*)d_ws;

  short* xb    = (short*)(ws + 0);                        // 16 MB
  short* WtQKV = (short*)(ws + (size_t)16*1024*1024);     // 12 MB [3072][2048]
  short* WoT   = (short*)(ws + (size_t)28*1024*1024);     //  8 MB [2048][2048]
  float* biasQ = (float*)(ws + (size_t)36*1024*1024);     // 12 KB
  short* qkv   = (short*)(ws + (size_t)37*1024*1024);     // 24 MB [4096][3072]
  short* Vt    = (short*)(ws + (size_t)61*1024*1024);     //  4 MB [B][KVH][128][2048]
  short* attn  = (short*)(ws + 0);                        // overlay xb (disjoint lifetime)

  k_cvt8<<<4096, 256, 0, stream>>>(x, xb);
  k_wtall<<<dim3(172,64), dim3(32,8), 0, stream>>>(Wq, Wk, Wv, Wo, bq, bk, bv,
                                                   WtQKV, WoT, biasQ);
  gemmR<3,1,1><<<dim3(8,32), 512, 0, stream>>>(xb, WtQKV, biasQ, qkv, Vt, 3072, 2048);
  k_attn<<<dim3(32,16,2), 256, 0, stream>>>(qkv, Vt, attn);
  gemmR<2,0,0><<<dim3(8,32), 512, 0, stream>>>(attn, WoT, bo, out, nullptr, 2048, 2048);
}